// Round 5
// baseline (632.348 us; speedup 1.0000x reference)
//
#include <hip/hip_runtime.h>
#include <hip/hip_bf16.h>

#define N_NODES 100000
#define N_EDGES 600000
#define N_REL   3
#define D_INF   256
#define D_OUTF  128

#define SCAN_TOTAL (3 * N_NODES)                 // 300000
#define SCAN_ELEMS 1024                          // elems per block
#define SCAN_NBLK  ((SCAN_TOTAL + SCAN_ELEMS - 1) / SCAN_ELEMS)  // 293

// ---------------------------------------------------------------------------
// K1: projection GEMM  l = relu(x@Wl+bl), r = relu(x@Wr+br)
// 128 thr (2 waves) = 32 col-groups (8 cols; 256 combined cols) x 4
// node-groups (8 nodes; 32 nodes/block).  Thread tile 8x8.
// Per k per wave: 2 ds_read_b128 (x, 24 LDS-cyc <= 32 budget) +
// 2 global float4 (W, L1-hot) + 64 FMA (128 SIMD-cyc)  -> FMA-bound.
// ---------------------------------------------------------------------------
__global__ __launch_bounds__(128) void proj_kernel(
    const float* __restrict__ x,
    const float* __restrict__ Wl, const float* __restrict__ bl,
    const float* __restrict__ Wr, const float* __restrict__ br,
    float* __restrict__ lbuf, float* __restrict__ rbuf)
{
    __shared__ float xs[32 * 256];
    const int tid = threadIdx.x;
    const int nb  = blockIdx.x * 32;

    const float4* xg  = reinterpret_cast<const float4*>(x + (size_t)nb * D_INF);
    float4*       xls = reinterpret_cast<float4*>(xs);
#pragma unroll
    for (int j = 0; j < 16; ++j) xls[tid + j * 128] = xg[tid + j * 128];
    __syncthreads();

    const int cg = tid & 31;   // col group: 8 cols each
    const int ng = tid >> 5;   // node group: 8 nodes each

    const float* wbase;
    const float* bbase;
    float*       obase;
    if (cg < 16) { wbase = Wl + 8 * cg;        bbase = bl + 8 * cg;        obase = lbuf + 8 * cg; }
    else         { wbase = Wr + 8 * (cg - 16); bbase = br + 8 * (cg - 16); obase = rbuf + 8 * (cg - 16); }

    float acc[8][8];
#pragma unroll
    for (int i = 0; i < 8; ++i)
#pragma unroll
        for (int j = 0; j < 8; ++j) acc[i][j] = 0.f;

    const float* xrow = xs + ng * 8 * 256;

    for (int k4 = 0; k4 < 64; ++k4) {
        // 8 nodes x 4 k's of x from LDS (vector reads, wave-broadcast)
        float4 xv[8];
#pragma unroll
        for (int i = 0; i < 8; ++i)
            xv[i] = *reinterpret_cast<const float4*>(xrow + i * 256 + k4 * 4);
#pragma unroll
        for (int j = 0; j < 4; ++j) {
            const float4 wa = *reinterpret_cast<const float4*>(wbase + (k4 * 4 + j) * D_OUTF);
            const float4 wb = *reinterpret_cast<const float4*>(wbase + (k4 * 4 + j) * D_OUTF + 4);
#pragma unroll
            for (int i = 0; i < 8; ++i) {
                const float xvj = (j == 0) ? xv[i].x : (j == 1) ? xv[i].y : (j == 2) ? xv[i].z : xv[i].w;
                acc[i][0] = fmaf(xvj, wa.x, acc[i][0]);
                acc[i][1] = fmaf(xvj, wa.y, acc[i][1]);
                acc[i][2] = fmaf(xvj, wa.z, acc[i][2]);
                acc[i][3] = fmaf(xvj, wa.w, acc[i][3]);
                acc[i][4] = fmaf(xvj, wb.x, acc[i][4]);
                acc[i][5] = fmaf(xvj, wb.y, acc[i][5]);
                acc[i][6] = fmaf(xvj, wb.z, acc[i][6]);
                acc[i][7] = fmaf(xvj, wb.w, acc[i][7]);
            }
        }
    }

    const float4 ba = *reinterpret_cast<const float4*>(bbase);
    const float4 bb = *reinterpret_cast<const float4*>(bbase + 4);
#pragma unroll
    for (int i = 0; i < 8; ++i) {
        const int node = nb + ng * 8 + i;
        float4 oa, ob;
        oa.x = fmaxf(acc[i][0] + ba.x, 0.f);
        oa.y = fmaxf(acc[i][1] + ba.y, 0.f);
        oa.z = fmaxf(acc[i][2] + ba.z, 0.f);
        oa.w = fmaxf(acc[i][3] + ba.w, 0.f);
        ob.x = fmaxf(acc[i][4] + bb.x, 0.f);
        ob.y = fmaxf(acc[i][5] + bb.y, 0.f);
        ob.z = fmaxf(acc[i][6] + bb.z, 0.f);
        ob.w = fmaxf(acc[i][7] + bb.w, 0.f);
        *reinterpret_cast<float4*>(obase + (size_t)node * D_OUTF)     = oa;
        *reinterpret_cast<float4*>(obase + (size_t)node * D_OUTF + 4) = ob;
    }
}

// ---------------------------------------------------------------------------
// K2: per-node attention scalars
// ---------------------------------------------------------------------------
__global__ __launch_bounds__(256) void alar_kernel(
    const float* __restrict__ lbuf, const float* __restrict__ rbuf,
    const float* __restrict__ attn, float* __restrict__ al, float* __restrict__ ar)
{
    const int t    = threadIdx.x;
    const int node = blockIdx.x * 2 + (t >> 7);
    const int hc   = t & 127;
    const int h    = hc >> 5;
    const int c    = hc & 31;
    const float lv = lbuf[(size_t)node * D_OUTF + hc];
    const float rv = rbuf[(size_t)node * D_OUTF + hc];
#pragma unroll
    for (int rr = 0; rr < 3; ++rr) {
        float pa = lv * attn[rr * 256 + h * 64 + c];
        float pb = rv * attn[rr * 256 + h * 64 + 32 + c];
#pragma unroll
        for (int m = 16; m >= 1; m >>= 1) {
            pa += __shfl_xor(pa, m);
            pb += __shfl_xor(pb, m);
        }
        if (c == 0) {
            al[node * 12 + rr * 4 + h] = pa;
            ar[node * 12 + rr * 4 + h] = pb;
        }
    }
}

// ---------------------------------------------------------------------------
// K3: degree histogram (by dst)
// ---------------------------------------------------------------------------
__global__ __launch_bounds__(256) void hist_kernel(const int* __restrict__ ei,
                                                   int* __restrict__ deg)
{
    const int rr = blockIdx.y;
    const int e  = blockIdx.x * 256 + threadIdx.x;
    if (e < N_EDGES) {
        const int dst = ei[(size_t)rr * 2 * N_EDGES + N_EDGES + e];
        atomicAdd(&deg[rr * N_NODES + dst], 1);
    }
}

// ---------------------------------------------------------------------------
// K4a: per-block reduce (1024 elems/block, 256 thr x 4)
// ---------------------------------------------------------------------------
__global__ __launch_bounds__(256) void scan_reduce(const int* __restrict__ deg,
                                                   int* __restrict__ blksum)
{
    __shared__ int ws[4];
    const int tid  = threadIdx.x;
    const int lane = tid & 63;
    const int wid  = tid >> 6;
    const int idx  = blockIdx.x * SCAN_ELEMS + tid * 4;
    int t = 0;
#pragma unroll
    for (int j = 0; j < 4; ++j)
        if (idx + j < SCAN_TOTAL) t += deg[idx + j];
#pragma unroll
    for (int off = 32; off >= 1; off >>= 1) t += __shfl_xor(t, off);
    if (lane == 0) ws[wid] = t;
    __syncthreads();
    if (tid == 0) blksum[blockIdx.x] = ws[0] + ws[1] + ws[2] + ws[3];
}

// ---------------------------------------------------------------------------
// K4b: single-block exclusive scan of the 293 block sums (512 threads)
// ---------------------------------------------------------------------------
__global__ __launch_bounds__(512) void scan_mid(int* __restrict__ blksum)
{
    __shared__ int sh[512];
    const int tid = threadIdx.x;
    const int v = (tid < SCAN_NBLK) ? blksum[tid] : 0;
    sh[tid] = v;
    __syncthreads();
#pragma unroll
    for (int off = 1; off < 512; off <<= 1) {
        const int u = (tid >= off) ? sh[tid - off] : 0;
        __syncthreads();
        sh[tid] += u;
        __syncthreads();
    }
    if (tid < SCAN_NBLK) blksum[tid] = sh[tid] - v;   // exclusive
}

// ---------------------------------------------------------------------------
// K4c: per-block scan + block offset -> rowst, cursor
// ---------------------------------------------------------------------------
__global__ __launch_bounds__(256) void scan_final(const int* __restrict__ deg,
    const int* __restrict__ blkoff, int* __restrict__ rowst,
    int* __restrict__ cursor)
{
    __shared__ int wsum[4];
    __shared__ int wexcl[4];
    const int tid  = threadIdx.x;
    const int lane = tid & 63;
    const int wid  = tid >> 6;
    const int idx  = blockIdx.x * SCAN_ELEMS + tid * 4;

    const int v0 = (idx + 0 < SCAN_TOTAL) ? deg[idx + 0] : 0;
    const int v1 = (idx + 1 < SCAN_TOTAL) ? deg[idx + 1] : 0;
    const int v2 = (idx + 2 < SCAN_TOTAL) ? deg[idx + 2] : 0;
    const int v3 = (idx + 3 < SCAN_TOTAL) ? deg[idx + 3] : 0;
    const int tsum = v0 + v1 + v2 + v3;
    int inc = tsum;
#pragma unroll
    for (int off = 1; off < 64; off <<= 1) {
        const int u = __shfl_up(inc, off);
        if (lane >= off) inc += u;
    }
    if (lane == 63) wsum[wid] = inc;
    __syncthreads();
    if (tid == 0) {
        int s = 0;
#pragma unroll
        for (int i = 0; i < 4; ++i) { const int t2 = wsum[i]; wexcl[i] = s; s += t2; }
    }
    __syncthreads();
    const int start = blkoff[blockIdx.x] + wexcl[wid] + (inc - tsum);
    if (idx + 0 < SCAN_TOTAL) { rowst[idx + 0] = start; cursor[idx + 0] = start; }
    const int s1 = start + v0;
    if (idx + 1 < SCAN_TOTAL) { rowst[idx + 1] = s1; cursor[idx + 1] = s1; }
    const int s2 = s1 + v1;
    if (idx + 2 < SCAN_TOTAL) { rowst[idx + 2] = s2; cursor[idx + 2] = s2; }
    const int s3 = s2 + v2;
    if (idx + 3 < SCAN_TOTAL) { rowst[idx + 3] = s3; cursor[idx + 3] = s3; }
}

// ---------------------------------------------------------------------------
// K5: scatter src ids into CSR buckets
// ---------------------------------------------------------------------------
__global__ __launch_bounds__(256) void scatter_kernel(const int* __restrict__ ei,
    int* __restrict__ cursor, int* __restrict__ colall)
{
    const int rr = blockIdx.y;
    const int e  = blockIdx.x * 256 + threadIdx.x;
    if (e < N_EDGES) {
        const int src = ei[(size_t)rr * 2 * N_EDGES + e];
        const int dst = ei[(size_t)rr * 2 * N_EDGES + N_EDGES + e];
        const int pos = atomicAdd(&cursor[rr * N_NODES + dst], 1);
        colall[pos] = src;
    }
}

// ---------------------------------------------------------------------------
// K6: fused per-node aggregation + relation-level beta softmax + output.
// One 64-lane wave per node; lane L owns channels hc0=L, hc1=L+64.
// Inner edge loop 2x-unrolled for memory-level parallelism.
// ---------------------------------------------------------------------------
__global__ __launch_bounds__(256) void aggregate_kernel(
    const float* __restrict__ lbuf, const float* __restrict__ rbuf,
    const float* __restrict__ al,   const float* __restrict__ ar,
    const int* __restrict__ rowst,  const int* __restrict__ deg,
    const int* __restrict__ colall,
    const float* __restrict__ rel_attn_l, const float* __restrict__ rel_attn_r,
    const float* __restrict__ rel_bias,   float* __restrict__ out)
{
    const int n    = (blockIdx.x * blockDim.x + threadIdx.x) >> 6;
    const int lane = threadIdx.x & 63;
    if (n >= N_NODES) return;

    const int h0  = lane >> 5;      // 0 or 1
    const int hc0 = lane;           // h0*32 + c
    const int hc1 = lane + 64;      // (h0+2)*32 + c

    float arr0[3], arr1[3];
#pragma unroll
    for (int rr = 0; rr < 3; ++rr) {
        arr0[rr] = ar[n * 12 + rr * 4 + h0];
        arr1[rr] = ar[n * 12 + rr * 4 + h0 + 2];
    }

    float emb0[3] = {0.f, 0.f, 0.f}, emb1[3] = {0.f, 0.f, 0.f};
    float den0[3] = {0.f, 0.f, 0.f}, den1[3] = {0.f, 0.f, 0.f};

#pragma unroll
    for (int rr = 0; rr < 3; ++rr) {
        const int start = rowst[rr * N_NODES + n];
        const int cnt   = deg[rr * N_NODES + n];
        for (int base = 0; base < cnt; base += 64) {
            const int m = min(64, cnt - base);
            const int srcv = (lane < m) ? colall[start + base + lane] : 0;
            int i = 0;
            for (; i + 1 < m; i += 2) {
                const int sA = __shfl(srcv, i);
                const int sB = __shfl(srcv, i + 1);
                const float alA0 = al[sA * 12 + rr * 4 + h0];
                const float alA1 = al[sA * 12 + rr * 4 + h0 + 2];
                const float alB0 = al[sB * 12 + rr * 4 + h0];
                const float alB1 = al[sB * 12 + rr * 4 + h0 + 2];
                const float* lrA = lbuf + (size_t)sA * D_OUTF;
                const float* lrB = lbuf + (size_t)sB * D_OUTF;
                const float lA0 = lrA[hc0], lA1 = lrA[hc1];
                const float lB0 = lrB[hc0], lB1 = lrB[hc1];
                float aA0 = alA0 + arr0[rr];
                float aA1 = alA1 + arr1[rr];
                float aB0 = alB0 + arr0[rr];
                float aB1 = alB1 + arr1[rr];
                aA0 = (aA0 > 0.f) ? aA0 : 0.2f * aA0;
                aA1 = (aA1 > 0.f) ? aA1 : 0.2f * aA1;
                aB0 = (aB0 > 0.f) ? aB0 : 0.2f * aB0;
                aB1 = (aB1 > 0.f) ? aB1 : 0.2f * aB1;
                const float wA0 = __expf(aA0), wA1 = __expf(aA1);
                const float wB0 = __expf(aB0), wB1 = __expf(aB1);
                den0[rr] += wA0 + wB0;
                den1[rr] += wA1 + wB1;
                emb0[rr] = fmaf(wA0, lA0, emb0[rr]);
                emb1[rr] = fmaf(wA1, lA1, emb1[rr]);
                emb0[rr] = fmaf(wB0, lB0, emb0[rr]);
                emb1[rr] = fmaf(wB1, lB1, emb1[rr]);
            }
            if (i < m) {
                const int src = __shfl(srcv, i);
                float a0 = al[src * 12 + rr * 4 + h0]     + arr0[rr];
                float a1 = al[src * 12 + rr * 4 + h0 + 2] + arr1[rr];
                a0 = (a0 > 0.f) ? a0 : 0.2f * a0;
                a1 = (a1 > 0.f) ? a1 : 0.2f * a1;
                const float w0 = __expf(a0);
                const float w1 = __expf(a1);
                den0[rr] += w0;
                den1[rr] += w1;
                const float* lr = lbuf + (size_t)src * D_OUTF;
                emb0[rr] = fmaf(w0, lr[hc0], emb0[rr]);
                emb1[rr] = fmaf(w1, lr[hc1], emb1[rr]);
            }
        }
    }

    // normalized relation embeddings + self slot
    float e0[4], e1[4];
#pragma unroll
    for (int rr = 0; rr < 3; ++rr) {
        e0[rr] = emb0[rr] / (den0[rr] + 1e-16f);
        e1[rr] = emb1[rr] / (den1[rr] + 1e-16f);
    }
    const float* lrn = lbuf + (size_t)n * D_OUTF;
    e0[3] = lrn[hc0];
    e1[3] = lrn[hc1];

    // relation-level beta attention
    const float rv0 = rbuf[(size_t)n * D_OUTF + hc0];
    const float rv1 = rbuf[(size_t)n * D_OUTF + hc1];
    const float bl0 = fmaxf(rv0 * rel_attn_l[hc0], 0.f);
    const float bl1 = fmaxf(rv1 * rel_attn_l[hc1], 0.f);

    float beta0[4], beta1[4];
#pragma unroll
    for (int s = 0; s < 4; ++s) {
        const float br0 = fmaxf(e0[s] * rel_attn_r[s * D_OUTF + hc0], 0.f);
        const float br1 = fmaxf(e1[s] * rel_attn_r[s * D_OUTF + hc1], 0.f);
        float p0 = bl0 * br0;
        float p1 = bl1 * br1;
#pragma unroll
        for (int m = 16; m >= 1; m >>= 1) {
            p0 += __shfl_xor(p0, m);
            p1 += __shfl_xor(p1, m);
        }
        beta0[s] = p0 + rel_bias[s];
        beta1[s] = p1 + rel_bias[s];
    }

    // softmax over the 4 relation slots (per head)
    float m0 = fmaxf(fmaxf(beta0[0], beta0[1]), fmaxf(beta0[2], beta0[3]));
    float m1 = fmaxf(fmaxf(beta1[0], beta1[1]), fmaxf(beta1[2], beta1[3]));
    float s0 = 0.f, s1 = 0.f;
#pragma unroll
    for (int s = 0; s < 4; ++s) {
        beta0[s] = __expf(beta0[s] - m0); s0 += beta0[s];
        beta1[s] = __expf(beta1[s] - m1); s1 += beta1[s];
    }
    const float is0 = 1.f / s0, is1 = 1.f / s1;
    float o0 = 0.f, o1 = 0.f;
#pragma unroll
    for (int s = 0; s < 4; ++s) {
        o0 = fmaf(e0[s], beta0[s] * is0, o0);
        o1 = fmaf(e1[s], beta1[s] * is1, o1);
    }
    out[(size_t)n * D_OUTF + hc0] = fmaxf(o0, 0.f);
    out[(size_t)n * D_OUTF + hc1] = fmaxf(o1, 0.f);
}

// ---------------------------------------------------------------------------
extern "C" void kernel_launch(void* const* d_in, const int* in_sizes, int n_in,
                              void* d_out, int out_size, void* d_ws, size_t ws_size,
                              hipStream_t stream)
{
    const float* x     = (const float*)d_in[0];
    const int*   ei    = (const int*)  d_in[1];
    const float* Wl    = (const float*)d_in[2];
    const float* bl    = (const float*)d_in[3];
    const float* Wr    = (const float*)d_in[4];
    const float* br    = (const float*)d_in[5];
    const float* attn  = (const float*)d_in[6];
    const float* ral   = (const float*)d_in[7];
    const float* rar   = (const float*)d_in[8];
    const float* rbias = (const float*)d_in[9];
    float* out = (float*)d_out;

    char* ws = (char*)d_ws;
    size_t off = 0;
    float* lbuf   = (float*)(ws + off); off += (size_t)N_NODES * D_OUTF * 4;   // 51.2 MB
    float* rbuf   = (float*)(ws + off); off += (size_t)N_NODES * D_OUTF * 4;   // 51.2 MB
    float* al     = (float*)(ws + off); off += (size_t)N_NODES * 12 * 4;       // 4.8 MB
    float* ar     = (float*)(ws + off); off += (size_t)N_NODES * 12 * 4;       // 4.8 MB
    int*   deg    = (int*)  (ws + off); off += (size_t)3 * N_NODES * 4;        // 1.2 MB
    int*   rowst  = (int*)  (ws + off); off += (size_t)3 * N_NODES * 4;        // 1.2 MB
    int*   cursor = (int*)  (ws + off); off += (size_t)3 * N_NODES * 4;        // 1.2 MB
    int*   colall = (int*)  (ws + off); off += (size_t)3 * N_EDGES * 4;        // 7.2 MB
    int*   blksum = (int*)  (ws + off); off += (size_t)512 * 4;

    hipMemsetAsync(deg, 0, (size_t)3 * N_NODES * 4, stream);

    proj_kernel<<<N_NODES / 32, 128, 0, stream>>>(x, Wl, bl, Wr, br, lbuf, rbuf);
    alar_kernel<<<N_NODES / 2, 256, 0, stream>>>(lbuf, rbuf, attn, al, ar);

    dim3 eg((N_EDGES + 255) / 256, 3);
    hist_kernel<<<eg, 256, 0, stream>>>(ei, deg);
    scan_reduce<<<SCAN_NBLK, 256, 0, stream>>>(deg, blksum);
    scan_mid<<<1, 512, 0, stream>>>(blksum);
    scan_final<<<SCAN_NBLK, 256, 0, stream>>>(deg, blksum, rowst, cursor);
    scatter_kernel<<<eg, 256, 0, stream>>>(ei, cursor, colall);

    aggregate_kernel<<<N_NODES / 4, 256, 0, stream>>>(
        lbuf, rbuf, al, ar, rowst, deg, colall, ral, rar, rbias, out);
}

// Round 6
// 513.104 us; speedup vs baseline: 1.2324x; 1.2324x over previous
//
#include <hip/hip_runtime.h>
#include <hip/hip_bf16.h>

#define N_NODES 100000
#define N_EDGES 600000
#define N_REL   3
#define D_INF   256
#define D_OUTF  128

#define SCAN_TOTAL (3 * N_NODES)                 // 300000
#define SCAN_ELEMS 1024                          // elems per block
#define SCAN_NBLK  ((SCAN_TOTAL + SCAN_ELEMS - 1) / SCAN_ELEMS)  // 293

typedef __attribute__((ext_vector_type(8))) short          bf16x8;
typedef __attribute__((ext_vector_type(8))) unsigned short ushort8;
typedef __attribute__((ext_vector_type(4))) float          f32x4;

// row stride (in bf16 elems) for LDS tiles: 72*2=144B -> 16B-aligned, and
// 16 rows spread over banks with only 2-way aliasing (free per m136)
#define LPAD 72

__device__ __forceinline__ unsigned short bf16_rne(float v) {
    unsigned int b = __float_as_uint(v);
    b += 0x7FFFu + ((b >> 16) & 1u);
    return (unsigned short)(b >> 16);
}

// ---------------------------------------------------------------------------
// K0: W [256][128] f32  ->  Wt_{hi,lo} [128 cols][256 k] bf16  (per W)
// layout: wt[w*65536 + plane*32768 + n*256 + k]
// ---------------------------------------------------------------------------
__global__ __launch_bounds__(128) void wt_prep(
    const float* __restrict__ Wl, const float* __restrict__ Wr,
    unsigned short* __restrict__ wt)
{
    const int k = blockIdx.x;      // 0..255
    const int w = blockIdx.y;      // 0,1
    const int n = threadIdx.x;     // 0..127
    const float v = (w ? Wr : Wl)[(size_t)k * D_OUTF + n];
    const unsigned short h = bf16_rne(v);
    const float fhi = __uint_as_float(((unsigned int)h) << 16);
    const unsigned short g = bf16_rne(v - fhi);
    const size_t base = (size_t)w * 2 * 128 * 256;
    wt[base + (size_t)n * 256 + k]          = h;
    wt[base + 32768 + (size_t)n * 256 + k]  = g;
}

// ---------------------------------------------------------------------------
// K1: projection GEMM via split-bf16 MFMA.
// grid = (ceil(N/64), 2): y=0 -> Wl/bl -> lbuf, y=1 -> Wr/br -> rbuf.
// block 256 thr (4 waves). Tile 64 nodes x 128 cols, K-blocked by 64.
// Wave wv owns rows [wv*16, wv*16+16); 8 col-frags of 16.
// C = xhi*Whi + xhi*Wlo + xlo*Whi  (error ~2^-16 rel).
// 16x16x32 frags: A[row=l&15][k=(l>>4)*8+j], B[k=(l>>4)*8+j][col=l&15],
// C[row=(l>>4)*4+j][col=l&15]  (C verified layout per m89).
// ---------------------------------------------------------------------------
__global__ __launch_bounds__(256) void proj_mfma(
    const float* __restrict__ x, const unsigned short* __restrict__ wt,
    const float* __restrict__ bl, const float* __restrict__ br,
    float* __restrict__ lbuf, float* __restrict__ rbuf)
{
    __shared__ unsigned short xs[2][64][LPAD];    // x tile   hi/lo
    __shared__ unsigned short ws2[2][128][LPAD];  // W^T tile hi/lo

    const int tid  = threadIdx.x;
    const int nb   = blockIdx.x * 64;
    const int w    = blockIdx.y;
    const unsigned short* wtw = wt + (size_t)w * 2 * 128 * 256;
    const float* bias = w ? br : bl;
    float*       obuf = w ? rbuf : lbuf;

    const int lane = tid & 63;
    const int wv   = tid >> 6;      // wave 0..3
    const int rowf = lane & 15;
    const int kgrp = lane >> 4;     // 0..3

    f32x4 acc[8];
#pragma unroll
    for (int cf = 0; cf < 8; ++cf) acc[cf] = (f32x4){0.f, 0.f, 0.f, 0.f};

    float bv[8];
#pragma unroll
    for (int cf = 0; cf < 8; ++cf) bv[cf] = bias[cf * 16 + rowf];

    for (int kb = 0; kb < D_INF; kb += 64) {
        __syncthreads();
        // ---- stage x tile: thread t -> row t>>2, 16 k's at (t&3)*16
        {
            const int r   = tid >> 2;
            const int seg = tid & 3;
            int rowg = nb + r; if (rowg >= N_NODES) rowg = N_NODES - 1;
            const float* src = x + (size_t)rowg * D_INF + kb + seg * 16;
#pragma unroll
            for (int q2 = 0; q2 < 2; ++q2) {
                const float4 v0 = *reinterpret_cast<const float4*>(src + q2 * 8);
                const float4 v1 = *reinterpret_cast<const float4*>(src + q2 * 8 + 4);
                const float vv[8] = {v0.x, v0.y, v0.z, v0.w, v1.x, v1.y, v1.z, v1.w};
                ushort8 hv, gv;
#pragma unroll
                for (int q = 0; q < 8; ++q) {
                    const unsigned short h = bf16_rne(vv[q]);
                    hv[q] = h;
                    const float fhi = __uint_as_float(((unsigned int)h) << 16);
                    gv[q] = bf16_rne(vv[q] - fhi);
                }
                *reinterpret_cast<ushort8*>(&xs[0][r][seg * 16 + q2 * 8]) = hv;
                *reinterpret_cast<ushort8*>(&xs[1][r][seg * 16 + q2 * 8]) = gv;
            }
        }
        // ---- stage W^T tile: thread t -> col n=t>>1, 32 k's at (t&1)*32
        {
            const int n    = tid >> 1;
            const int half = tid & 1;
            const uint4* sh = reinterpret_cast<const uint4*>(wtw + (size_t)n * 256 + kb + half * 32);
            const uint4* sl = reinterpret_cast<const uint4*>(wtw + 32768 + (size_t)n * 256 + kb + half * 32);
            uint4* dh = reinterpret_cast<uint4*>(&ws2[0][n][half * 32]);
            uint4* dl = reinterpret_cast<uint4*>(&ws2[1][n][half * 32]);
#pragma unroll
            for (int q = 0; q < 4; ++q) { dh[q] = sh[q]; dl[q] = sl[q]; }
        }
        __syncthreads();

        // ---- MFMA over the 2 k32-steps of this BK
#pragma unroll
        for (int kk = 0; kk < 2; ++kk) {
            const int ko = kk * 32 + kgrp * 8;
            const bf16x8 ahi = *reinterpret_cast<const bf16x8*>(&xs[0][wv * 16 + rowf][ko]);
            const bf16x8 alo = *reinterpret_cast<const bf16x8*>(&xs[1][wv * 16 + rowf][ko]);
#pragma unroll
            for (int cf = 0; cf < 8; ++cf) {
                const bf16x8 bhi = *reinterpret_cast<const bf16x8*>(&ws2[0][cf * 16 + rowf][ko]);
                const bf16x8 blo = *reinterpret_cast<const bf16x8*>(&ws2[1][cf * 16 + rowf][ko]);
                acc[cf] = __builtin_amdgcn_mfma_f32_16x16x32_bf16(ahi, bhi, acc[cf], 0, 0, 0);
                acc[cf] = __builtin_amdgcn_mfma_f32_16x16x32_bf16(ahi, blo, acc[cf], 0, 0, 0);
                acc[cf] = __builtin_amdgcn_mfma_f32_16x16x32_bf16(alo, bhi, acc[cf], 0, 0, 0);
            }
        }
    }

    // ---- epilogue: bias + relu + store (C layout: row=kgrp*4+j, col=rowf)
#pragma unroll
    for (int cf = 0; cf < 8; ++cf) {
#pragma unroll
        for (int j = 0; j < 4; ++j) {
            const int node = nb + wv * 16 + kgrp * 4 + j;
            if (node < N_NODES)
                obuf[(size_t)node * D_OUTF + cf * 16 + rowf] =
                    fmaxf(acc[cf][j] + bv[cf], 0.f);
        }
    }
}

// ---------------------------------------------------------------------------
// K2: per-node attention scalars
// ---------------------------------------------------------------------------
__global__ __launch_bounds__(256) void alar_kernel(
    const float* __restrict__ lbuf, const float* __restrict__ rbuf,
    const float* __restrict__ attn, float* __restrict__ al, float* __restrict__ ar)
{
    const int t    = threadIdx.x;
    const int node = blockIdx.x * 2 + (t >> 7);
    const int hc   = t & 127;
    const int h    = hc >> 5;
    const int c    = hc & 31;
    const float lv = lbuf[(size_t)node * D_OUTF + hc];
    const float rv = rbuf[(size_t)node * D_OUTF + hc];
#pragma unroll
    for (int rr = 0; rr < 3; ++rr) {
        float pa = lv * attn[rr * 256 + h * 64 + c];
        float pb = rv * attn[rr * 256 + h * 64 + 32 + c];
#pragma unroll
        for (int m = 16; m >= 1; m >>= 1) {
            pa += __shfl_xor(pa, m);
            pb += __shfl_xor(pb, m);
        }
        if (c == 0) {
            al[node * 12 + rr * 4 + h] = pa;
            ar[node * 12 + rr * 4 + h] = pb;
        }
    }
}

// ---------------------------------------------------------------------------
// K3: degree histogram (by dst)
// ---------------------------------------------------------------------------
__global__ __launch_bounds__(256) void hist_kernel(const int* __restrict__ ei,
                                                   int* __restrict__ deg)
{
    const int rr = blockIdx.y;
    const int e  = blockIdx.x * 256 + threadIdx.x;
    if (e < N_EDGES) {
        const int dst = ei[(size_t)rr * 2 * N_EDGES + N_EDGES + e];
        atomicAdd(&deg[rr * N_NODES + dst], 1);
    }
}

// ---------------------------------------------------------------------------
// K4a: per-block reduce (1024 elems/block, 256 thr x 4)
// ---------------------------------------------------------------------------
__global__ __launch_bounds__(256) void scan_reduce(const int* __restrict__ deg,
                                                   int* __restrict__ blksum)
{
    __shared__ int ws[4];
    const int tid  = threadIdx.x;
    const int lane = tid & 63;
    const int wid  = tid >> 6;
    const int idx  = blockIdx.x * SCAN_ELEMS + tid * 4;
    int t = 0;
#pragma unroll
    for (int j = 0; j < 4; ++j)
        if (idx + j < SCAN_TOTAL) t += deg[idx + j];
#pragma unroll
    for (int off = 32; off >= 1; off >>= 1) t += __shfl_xor(t, off);
    if (lane == 0) ws[wid] = t;
    __syncthreads();
    if (tid == 0) blksum[blockIdx.x] = ws[0] + ws[1] + ws[2] + ws[3];
}

// ---------------------------------------------------------------------------
// K4b: single-block exclusive scan of the 293 block sums (512 threads)
// ---------------------------------------------------------------------------
__global__ __launch_bounds__(512) void scan_mid(int* __restrict__ blksum)
{
    __shared__ int sh[512];
    const int tid = threadIdx.x;
    const int v = (tid < SCAN_NBLK) ? blksum[tid] : 0;
    sh[tid] = v;
    __syncthreads();
#pragma unroll
    for (int off = 1; off < 512; off <<= 1) {
        const int u = (tid >= off) ? sh[tid - off] : 0;
        __syncthreads();
        sh[tid] += u;
        __syncthreads();
    }
    if (tid < SCAN_NBLK) blksum[tid] = sh[tid] - v;   // exclusive
}

// ---------------------------------------------------------------------------
// K4c: per-block scan + block offset -> rowst, cursor
// ---------------------------------------------------------------------------
__global__ __launch_bounds__(256) void scan_final(const int* __restrict__ deg,
    const int* __restrict__ blkoff, int* __restrict__ rowst,
    int* __restrict__ cursor)
{
    __shared__ int wsum[4];
    __shared__ int wexcl[4];
    const int tid  = threadIdx.x;
    const int lane = tid & 63;
    const int wid  = tid >> 6;
    const int idx  = blockIdx.x * SCAN_ELEMS + tid * 4;

    const int v0 = (idx + 0 < SCAN_TOTAL) ? deg[idx + 0] : 0;
    const int v1 = (idx + 1 < SCAN_TOTAL) ? deg[idx + 1] : 0;
    const int v2 = (idx + 2 < SCAN_TOTAL) ? deg[idx + 2] : 0;
    const int v3 = (idx + 3 < SCAN_TOTAL) ? deg[idx + 3] : 0;
    const int tsum = v0 + v1 + v2 + v3;
    int inc = tsum;
#pragma unroll
    for (int off = 1; off < 64; off <<= 1) {
        const int u = __shfl_up(inc, off);
        if (lane >= off) inc += u;
    }
    if (lane == 63) wsum[wid] = inc;
    __syncthreads();
    if (tid == 0) {
        int s = 0;
#pragma unroll
        for (int i = 0; i < 4; ++i) { const int t2 = wsum[i]; wexcl[i] = s; s += t2; }
    }
    __syncthreads();
    const int start = blkoff[blockIdx.x] + wexcl[wid] + (inc - tsum);
    if (idx + 0 < SCAN_TOTAL) { rowst[idx + 0] = start; cursor[idx + 0] = start; }
    const int s1 = start + v0;
    if (idx + 1 < SCAN_TOTAL) { rowst[idx + 1] = s1; cursor[idx + 1] = s1; }
    const int s2 = s1 + v1;
    if (idx + 2 < SCAN_TOTAL) { rowst[idx + 2] = s2; cursor[idx + 2] = s2; }
    const int s3 = s2 + v2;
    if (idx + 3 < SCAN_TOTAL) { rowst[idx + 3] = s3; cursor[idx + 3] = s3; }
}

// ---------------------------------------------------------------------------
// K5: scatter src ids into CSR buckets
// ---------------------------------------------------------------------------
__global__ __launch_bounds__(256) void scatter_kernel(const int* __restrict__ ei,
    int* __restrict__ cursor, int* __restrict__ colall)
{
    const int rr = blockIdx.y;
    const int e  = blockIdx.x * 256 + threadIdx.x;
    if (e < N_EDGES) {
        const int src = ei[(size_t)rr * 2 * N_EDGES + e];
        const int dst = ei[(size_t)rr * 2 * N_EDGES + N_EDGES + e];
        const int pos = atomicAdd(&cursor[rr * N_NODES + dst], 1);
        colall[pos] = src;
    }
}

// ---------------------------------------------------------------------------
// K6: fused per-node aggregation + relation-level beta softmax + output.
// ---------------------------------------------------------------------------
__global__ __launch_bounds__(256) void aggregate_kernel(
    const float* __restrict__ lbuf, const float* __restrict__ rbuf,
    const float* __restrict__ al,   const float* __restrict__ ar,
    const int* __restrict__ rowst,  const int* __restrict__ deg,
    const int* __restrict__ colall,
    const float* __restrict__ rel_attn_l, const float* __restrict__ rel_attn_r,
    const float* __restrict__ rel_bias,   float* __restrict__ out)
{
    const int n    = (blockIdx.x * blockDim.x + threadIdx.x) >> 6;
    const int lane = threadIdx.x & 63;
    if (n >= N_NODES) return;

    const int h0  = lane >> 5;      // 0 or 1
    const int hc0 = lane;           // h0*32 + c
    const int hc1 = lane + 64;      // (h0+2)*32 + c

    float arr0[3], arr1[3];
#pragma unroll
    for (int rr = 0; rr < 3; ++rr) {
        arr0[rr] = ar[n * 12 + rr * 4 + h0];
        arr1[rr] = ar[n * 12 + rr * 4 + h0 + 2];
    }

    float emb0[3] = {0.f, 0.f, 0.f}, emb1[3] = {0.f, 0.f, 0.f};
    float den0[3] = {0.f, 0.f, 0.f}, den1[3] = {0.f, 0.f, 0.f};

#pragma unroll
    for (int rr = 0; rr < 3; ++rr) {
        const int start = rowst[rr * N_NODES + n];
        const int cnt   = deg[rr * N_NODES + n];
        for (int base = 0; base < cnt; base += 64) {
            const int m = min(64, cnt - base);
            const int srcv = (lane < m) ? colall[start + base + lane] : 0;
            int i = 0;
            for (; i + 1 < m; i += 2) {
                const int sA = __shfl(srcv, i);
                const int sB = __shfl(srcv, i + 1);
                const float alA0 = al[sA * 12 + rr * 4 + h0];
                const float alA1 = al[sA * 12 + rr * 4 + h0 + 2];
                const float alB0 = al[sB * 12 + rr * 4 + h0];
                const float alB1 = al[sB * 12 + rr * 4 + h0 + 2];
                const float* lrA = lbuf + (size_t)sA * D_OUTF;
                const float* lrB = lbuf + (size_t)sB * D_OUTF;
                const float lA0 = lrA[hc0], lA1 = lrA[hc1];
                const float lB0 = lrB[hc0], lB1 = lrB[hc1];
                float aA0 = alA0 + arr0[rr];
                float aA1 = alA1 + arr1[rr];
                float aB0 = alB0 + arr0[rr];
                float aB1 = alB1 + arr1[rr];
                aA0 = (aA0 > 0.f) ? aA0 : 0.2f * aA0;
                aA1 = (aA1 > 0.f) ? aA1 : 0.2f * aA1;
                aB0 = (aB0 > 0.f) ? aB0 : 0.2f * aB0;
                aB1 = (aB1 > 0.f) ? aB1 : 0.2f * aB1;
                const float wA0 = __expf(aA0), wA1 = __expf(aA1);
                const float wB0 = __expf(aB0), wB1 = __expf(aB1);
                den0[rr] += wA0 + wB0;
                den1[rr] += wA1 + wB1;
                emb0[rr] = fmaf(wA0, lA0, emb0[rr]);
                emb1[rr] = fmaf(wA1, lA1, emb1[rr]);
                emb0[rr] = fmaf(wB0, lB0, emb0[rr]);
                emb1[rr] = fmaf(wB1, lB1, emb1[rr]);
            }
            if (i < m) {
                const int src = __shfl(srcv, i);
                float a0 = al[src * 12 + rr * 4 + h0]     + arr0[rr];
                float a1 = al[src * 12 + rr * 4 + h0 + 2] + arr1[rr];
                a0 = (a0 > 0.f) ? a0 : 0.2f * a0;
                a1 = (a1 > 0.f) ? a1 : 0.2f * a1;
                const float w0 = __expf(a0);
                const float w1 = __expf(a1);
                den0[rr] += w0;
                den1[rr] += w1;
                const float* lr = lbuf + (size_t)src * D_OUTF;
                emb0[rr] = fmaf(w0, lr[hc0], emb0[rr]);
                emb1[rr] = fmaf(w1, lr[hc1], emb1[rr]);
            }
        }
    }

    // normalized relation embeddings + self slot
    float e0[4], e1[4];
#pragma unroll
    for (int rr = 0; rr < 3; ++rr) {
        e0[rr] = emb0[rr] / (den0[rr] + 1e-16f);
        e1[rr] = emb1[rr] / (den1[rr] + 1e-16f);
    }
    const float* lrn = lbuf + (size_t)n * D_OUTF;
    e0[3] = lrn[hc0];
    e1[3] = lrn[hc1];

    // relation-level beta attention
    const float rv0 = rbuf[(size_t)n * D_OUTF + hc0];
    const float rv1 = rbuf[(size_t)n * D_OUTF + hc1];
    const float bl0 = fmaxf(rv0 * rel_attn_l[hc0], 0.f);
    const float bl1 = fmaxf(rv1 * rel_attn_l[hc1], 0.f);

    float beta0[4], beta1[4];
#pragma unroll
    for (int s = 0; s < 4; ++s) {
        const float br0 = fmaxf(e0[s] * rel_attn_r[s * D_OUTF + hc0], 0.f);
        const float br1 = fmaxf(e1[s] * rel_attn_r[s * D_OUTF + hc1], 0.f);
        float p0 = bl0 * br0;
        float p1 = bl1 * br1;
#pragma unroll
        for (int m = 16; m >= 1; m >>= 1) {
            p0 += __shfl_xor(p0, m);
            p1 += __shfl_xor(p1, m);
        }
        beta0[s] = p0 + rel_bias[s];
        beta1[s] = p1 + rel_bias[s];
    }

    // softmax over the 4 relation slots (per head)
    float m0 = fmaxf(fmaxf(beta0[0], beta0[1]), fmaxf(beta0[2], beta0[3]));
    float m1 = fmaxf(fmaxf(beta1[0], beta1[1]), fmaxf(beta1[2], beta1[3]));
    float s0 = 0.f, s1 = 0.f;
#pragma unroll
    for (int s = 0; s < 4; ++s) {
        beta0[s] = __expf(beta0[s] - m0); s0 += beta0[s];
        beta1[s] = __expf(beta1[s] - m1); s1 += beta1[s];
    }
    const float is0 = 1.f / s0, is1 = 1.f / s1;
    float o0 = 0.f, o1 = 0.f;
#pragma unroll
    for (int s = 0; s < 4; ++s) {
        o0 = fmaf(e0[s], beta0[s] * is0, o0);
        o1 = fmaf(e1[s], beta1[s] * is1, o1);
    }
    out[(size_t)n * D_OUTF + hc0] = fmaxf(o0, 0.f);
    out[(size_t)n * D_OUTF + hc1] = fmaxf(o1, 0.f);
}

// ---------------------------------------------------------------------------
extern "C" void kernel_launch(void* const* d_in, const int* in_sizes, int n_in,
                              void* d_out, int out_size, void* d_ws, size_t ws_size,
                              hipStream_t stream)
{
    const float* x     = (const float*)d_in[0];
    const int*   ei    = (const int*)  d_in[1];
    const float* Wl    = (const float*)d_in[2];
    const float* bl    = (const float*)d_in[3];
    const float* Wr    = (const float*)d_in[4];
    const float* br    = (const float*)d_in[5];
    const float* attn  = (const float*)d_in[6];
    const float* ral   = (const float*)d_in[7];
    const float* rar   = (const float*)d_in[8];
    const float* rbias = (const float*)d_in[9];
    float* out = (float*)d_out;

    char* ws = (char*)d_ws;
    size_t off = 0;
    float* lbuf   = (float*)(ws + off); off += (size_t)N_NODES * D_OUTF * 4;   // 51.2 MB
    float* rbuf   = (float*)(ws + off); off += (size_t)N_NODES * D_OUTF * 4;   // 51.2 MB
    float* al     = (float*)(ws + off); off += (size_t)N_NODES * 12 * 4;       // 4.8 MB
    float* ar     = (float*)(ws + off); off += (size_t)N_NODES * 12 * 4;       // 4.8 MB
    int*   deg    = (int*)  (ws + off); off += (size_t)3 * N_NODES * 4;        // 1.2 MB
    int*   rowst  = (int*)  (ws + off); off += (size_t)3 * N_NODES * 4;        // 1.2 MB
    int*   cursor = (int*)  (ws + off); off += (size_t)3 * N_NODES * 4;        // 1.2 MB
    int*   colall = (int*)  (ws + off); off += (size_t)3 * N_EDGES * 4;        // 7.2 MB
    int*   blksum = (int*)  (ws + off); off += (size_t)512 * 4;
    unsigned short* wt = (unsigned short*)(ws + off); off += (size_t)2 * 2 * 128 * 256 * 2; // 256 KB

    hipMemsetAsync(deg, 0, (size_t)3 * N_NODES * 4, stream);

    wt_prep<<<dim3(256, 2), 128, 0, stream>>>(Wl, Wr, wt);
    proj_mfma<<<dim3((N_NODES + 63) / 64, 2), 256, 0, stream>>>(
        x, wt, bl, br, lbuf, rbuf);

    alar_kernel<<<N_NODES / 2, 256, 0, stream>>>(lbuf, rbuf, attn, al, ar);

    dim3 eg((N_EDGES + 255) / 256, 3);
    hist_kernel<<<eg, 256, 0, stream>>>(ei, deg);
    scan_reduce<<<SCAN_NBLK, 256, 0, stream>>>(deg, blksum);
    scan_mid<<<1, 512, 0, stream>>>(blksum);
    scan_final<<<SCAN_NBLK, 256, 0, stream>>>(deg, blksum, rowst, cursor);
    scatter_kernel<<<eg, 256, 0, stream>>>(ei, cursor, colall);

    aggregate_kernel<<<N_NODES / 4, 256, 0, stream>>>(
        lbuf, rbuf, al, ar, rowst, deg, colall, ral, rar, rbias, out);
}